// Round 11
// baseline (166.677 us; speedup 1.0000x reference)
//
#include <hip/hip_runtime.h>
#include <hip/hip_bf16.h>

// Round-14: qkv/proj -> bf16 MFMA GEMMs (-33us).
// Round-15/16: coalesced prepass, fragment-tiled xb2 (-17us).
// Round-19: fragment-tiled ALL MFMA operands (-18us).
// Round-20: merged 6->4 launches + exp2 softmax (-6.7us, 145.2us verified).
// Round-21/22: grid-sync fusion -> harness deaths.  OFF THE TABLE.
// Round-23: conv 2-half split -> REGRESSED (155.0) but exposed tail in
//   top-5: 43.1us, MfmaUtil 8.7%, VALUBusy 6%, Occ 19% = latency-bound;
//   conv arithmetic is ~4us of MFMA.  Diagnosis: (a) oh=0/oh=1 blocks
//   stage IDENTICAL 52KB x-tiles (2x redundant), (b) per-block compute
//   phase too short to amortize staging latency, (c) split doubled the
//   serialized phases.
// Round-24 (this): merge the oh halves -- one conv block = all 256 out-ch
//   (wave owns o16 in {w,w+4,w+8,w+12}, 8 accs), single 53.9KB stage.
//   Staging traffic halves, MFMA density/block doubles, phases 2->1.
//   Tail grid = 256 conv + 256 proj.  All else identical to round 10.

typedef __hip_bfloat16 bf16;
using short8 = __attribute__((ext_vector_type(8))) short;
using short4v = __attribute__((ext_vector_type(4))) short;
using f32x4 = __attribute__((ext_vector_type(4))) float;

__device__ __forceinline__ short f2bs(float f) {
  union { bf16 b; short s; } u; u.b = __float2bfloat16(f); return u.s;
}
__device__ __forceinline__ float bs2f(short s) {
  union { unsigned u; float f; } x; x.u = ((unsigned)(unsigned short)s) << 16;
  return x.f;
}
__device__ __forceinline__ float fexp2(float x) {
  float r; asm("v_exp_f32 %0, %1" : "=v"(r) : "v"(x)); return r;
}

// Fragment-tile address for a [O][256] bf16 weight matrix.
__device__ __forceinline__ size_t wtile(int o, int c) {
  return ((size_t)((o >> 4) * 8 + (c >> 5)) * 512) +
         (((c >> 3) & 3) * 16 + (o & 15)) * 8 + (c & 7);
}

// ---------------------------------------------------------------------------
// Kernel 0 (prep): xpose + all weight packs, blockIdx-partitioned.
// grid 1552, block 256.  LDS: union of xls (16896B) / ws (9216B).
// ---------------------------------------------------------------------------
__global__ __launch_bounds__(256) void prep(
    const float* __restrict__ X, short* __restrict__ xt,
    short* __restrict__ xb2,
    const float* __restrict__ Wc, short* __restrict__ Wb2,
    const float* __restrict__ wq, short* __restrict__ Wq2,
    const float* __restrict__ wa, short* __restrict__ Wa2) {
  __shared__ __align__(16) char smem[16896];
  const int bid = blockIdx.x;
  const int tid = threadIdx.x;
  if (bid < 272) {
    const int b = bid / 34, r = bid - (bid / 34) * 34;   // r in 0..33
    if (r == 0 || r == 33) {                  // full zero halo row
      short8 z = {};
      short* dst = xt + (((size_t)b * 34 + r) * 34) * 256;
      for (int g = tid; g < 1088; g += 256) *(short8*)(dst + g * 8) = z;
      return;
    }
    short (*xls)[264] = (short(*)[264])smem;  // [p][c], pitch 264
    {
      const float* src = X + (size_t)b * 256 * 1024 + (r - 1) * 32;
      for (int it = 0; it < 8; ++it) {
        int idx = it * 256 + tid;
        int c = idx >> 3, pq = idx & 7;
        float4 f4 = *(const float4*)(src + (size_t)c * 1024 + pq * 4);
        xls[pq * 4 + 0][c] = f2bs(f4.x);
        xls[pq * 4 + 1][c] = f2bs(f4.y);
        xls[pq * 4 + 2][c] = f2bs(f4.z);
        xls[pq * 4 + 3][c] = f2bs(f4.w);
      }
    }
    __syncthreads();
    {
      short* dst = xt + (((size_t)b * 34 + r) * 34) * 256;
      for (int it = 0; it < 4; ++it) {
        int idx = it * 256 + tid;
        int cc = idx >> 5, co = idx & 31;
        short8 v = *(const short8*)&xls[cc][co * 8];
        *(short8*)(dst + (cc + 1) * 256 + co * 8) = v;
      }
      if (tid < 64) {
        short8 z = {};
        int cce = (tid >> 5) * 33, co = tid & 31;
        *(short8*)(dst + cce * 256 + co * 8) = z;
      }
    }
    {
      short* dst = xb2 + (((size_t)b * 64 + (r - 1) * 2) * 8) * 512;
      for (int it = 0; it < 4; ++it) {
        int g = it * 256 + tid;
        int half = g >> 9, c8 = (g >> 6) & 7, grp = (g >> 4) & 3, pcol = g & 15;
        short8 v = *(const short8*)&xls[half * 16 + pcol][c8 * 32 + grp * 8];
        *(short8*)(dst + ((half * 8 + c8) * 64 + grp * 16 + pcol) * 8) = v;
      }
    }
  } else if (bid < 528) {
    float* ws = (float*)smem;                  // one o's [c][tap] block
    const int o = bid - 272;
    const float* src = Wc + (size_t)o * 2304;
    for (int it = 0; it < 9; ++it) ws[it * 256 + tid] = src[it * 256 + tid];
    __syncthreads();
#pragma unroll
    for (int tap = 0; tap < 9; ++tap)
      Wb2[(size_t)tap * 65536 + wtile(o, tid)] = f2bs(ws[tid * 9 + tap]);
  } else if (bid < 1296) {
    const int o = bid - 528;
    Wq2[wtile(o, tid)] = f2bs(wq[o * 256 + tid]);
  } else {
    const int o = bid - 1296;
    Wa2[wtile(o, tid)] = f2bs(wa[o * 256 + tid]);
  }
}

// ---------------------------------------------------------------------------
// Kernel 1: QKV 1x1 conv as bf16 MFMA GEMM, all operands lane-linear.
// grid (16, 6, 8), block 256.
// ---------------------------------------------------------------------------
__global__ __launch_bounds__(256) void qkv_mfma(
    const short* __restrict__ Wq2, const short* __restrict__ xb2,
    const float* __restrict__ bias,
    short* __restrict__ qsb, short* __restrict__ ksb2, short* __restrict__ vtb2) {
  const int tid = threadIdx.x;
  const int w = tid >> 6, lane = tid & 63;
  const int col = lane & 15, grp = lane >> 4;
  const int b = blockIdx.z;
  const int bx = blockIdx.x;
  const int p0 = bx * 64;
  const int ob = blockIdx.y * 128 + w * 16;
  const int o16 = ob >> 4;

  const short* wbase = Wq2 + lane * 8;
  const short* xpb = xb2 + (((size_t)b * 64 + bx * 4) * 8) * 512 + lane * 8;

  f32x4 acc[2][4] = {};
#pragma unroll
  for (int c8 = 0; c8 < 8; ++c8) {
    short8 a0 = *(const short8*)(wbase + (size_t)(o16 * 8 + c8) * 512);
    short8 a1 = *(const short8*)(wbase + (size_t)((o16 + 4) * 8 + c8) * 512);
    short8 b0 = *(const short8*)(xpb + c8 * 512);
    short8 b1 = *(const short8*)(xpb + 4096 + c8 * 512);
    short8 b2 = *(const short8*)(xpb + 8192 + c8 * 512);
    short8 b3 = *(const short8*)(xpb + 12288 + c8 * 512);
    acc[0][0] = __builtin_amdgcn_mfma_f32_16x16x32_bf16(a0, b0, acc[0][0], 0, 0, 0);
    acc[0][1] = __builtin_amdgcn_mfma_f32_16x16x32_bf16(a0, b1, acc[0][1], 0, 0, 0);
    acc[0][2] = __builtin_amdgcn_mfma_f32_16x16x32_bf16(a0, b2, acc[0][2], 0, 0, 0);
    acc[0][3] = __builtin_amdgcn_mfma_f32_16x16x32_bf16(a0, b3, acc[0][3], 0, 0, 0);
    acc[1][0] = __builtin_amdgcn_mfma_f32_16x16x32_bf16(a1, b0, acc[1][0], 0, 0, 0);
    acc[1][1] = __builtin_amdgcn_mfma_f32_16x16x32_bf16(a1, b1, acc[1][1], 0, 0, 0);
    acc[1][2] = __builtin_amdgcn_mfma_f32_16x16x32_bf16(a1, b2, acc[1][2], 0, 0, 0);
    acc[1][3] = __builtin_amdgcn_mfma_f32_16x16x32_bf16(a1, b3, acc[1][3], 0, 0, 0);
  }

  const float qscale = 0.25503486f;  // 32^-0.5 * log2(e)
#pragma unroll
  for (int j = 0; j < 2; ++j) {
    const int obase = ob + j * 64 + grp * 4;
    const int sect = obase >> 8;
    const int nh = (obase >> 5) & 7;
    const int d0 = obase & 31;
    const size_t hb = ((size_t)(b * 8 + nh)) * 1024;
    const size_t hb2 = ((size_t)(b * 8 + nh)) * 32768;
    float bv[4];
#pragma unroll
    for (int r = 0; r < 4; ++r) bv[r] = bias[obase + r];
    if (sect == 0) {
#pragma unroll
      for (int pp = 0; pp < 4; ++pp) {
        const int p = p0 + pp * 16 + col;
        short4v o4;
#pragma unroll
        for (int r = 0; r < 4; ++r)
          o4[r] = f2bs((acc[j][pp][r] + bv[r]) * qscale);
        *(short4v*)&qsb[(hb + p) * 32 + d0] = o4;
      }
    } else if (sect == 1) {
      const size_t kb = hb2 + (size_t)bx * 2048 + (w & 1) * 256 +
                        (grp >> 1) * 128 + col * 8 + (grp & 1) * 4;
#pragma unroll
      for (int pp = 0; pp < 4; ++pp) {
        short4v o4;
#pragma unroll
        for (int r = 0; r < 4; ++r)
          o4[r] = f2bs(acc[j][pp][r] + bv[r]);
        *(short4v*)&ksb2[kb + pp * 512] = o4;
      }
    } else {
      const size_t vb0 = hb2 + (size_t)bx * 2048 + (size_t)(w & 1) * 512 +
                         (col >> 3) * 128 + (grp * 4) * 8 + (col & 7);
#pragma unroll
      for (int pp = 0; pp < 4; ++pp) {
        const size_t vb = vb0 + (pp >> 1) * 1024 + (pp & 1) * 256;
#pragma unroll
        for (int r = 0; r < 4; ++r)
          vtb2[vb + r * 8] = f2bs(acc[j][pp][r] + bv[r]);
      }
    }
  }
}

// ---------------------------------------------------------------------------
// Kernel 2: pipelined transposed MFMA flash attention; lane-linear K/V
// staging; exp2 softmax.  grid (16, 64), block 256.  LDS 35.3KB, 4 blk/CU.
// ---------------------------------------------------------------------------
__global__ __launch_bounds__(256, 4) void attn_mfma(
    const short* __restrict__ qsb, const short* __restrict__ ksb2,
    const short* __restrict__ vtb2,
    const float* __restrict__ relw_g, const float* __restrict__ relh_g,
    short* __restrict__ amt2) {
  const int tid = threadIdx.x;
  const int w = tid >> 6, lane = tid & 63;
  const int col = lane & 15, grp = lane >> 4, g8 = grp * 8;
  const int qt = blockIdx.x * 4 + w;       // q-tile 0..63
  const int bnh = blockIdx.y;
  const int q0 = qt * 16;
  const int i = qt >> 1;
  const int j0 = (qt & 1) * 16;

  const short* Qb = qsb + (size_t)bnh * 32768;

  __shared__ short Gh_s[4][16][68];     // [wave][q][m]        8704B
  __shared__ short kvb[2][8][512];      // [slot][frag][...]  16384B
  __shared__ short Pt_s[4][2][16][40];  // [wave][half][q][key] 10240B
  short* Gw_w = &Pt_s[w][0][0][0];      // scratch alias (wave-private)

  const short* gK = ksb2 + (size_t)bnh * 32768 + w * 512 + lane * 8;
  const short* gV = vtb2 + (size_t)bnh * 32768 + w * 512 + lane * 8;

  short8 stgK = *(const short8*)gK;
  short8 stgV = *(const short8*)gV;

  short8 b_q = *(const short8*)(Qb + (q0 + col) * 32 + g8);

  {
    const float* rels[2] = {relh_g, relw_g};
#pragma unroll
    for (int tb = 0; tb < 2; ++tb) {
      const float* relg = rels[tb];
#pragma unroll
      for (int t = 0; t < 4; ++t) {
        int m = 16 * t + col;
        int mc = m > 62 ? 62 : m;
        const float* rp = relg + mc * 32 + g8;
        float4 f0 = *(const float4*)rp;
        float4 f1 = *(const float4*)(rp + 4);
        short8 ar;
        ar[0] = f2bs(f0.x); ar[1] = f2bs(f0.y);
        ar[2] = f2bs(f0.z); ar[3] = f2bs(f0.w);
        ar[4] = f2bs(f1.x); ar[5] = f2bs(f1.y);
        ar[6] = f2bs(f1.z); ar[7] = f2bs(f1.w);
        f32x4 d = __builtin_amdgcn_mfma_f32_16x16x32_bf16(
            ar, b_q, (f32x4){0.f, 0.f, 0.f, 0.f}, 0, 0, 0);
        short4v o;
        o[0] = f2bs(d[0]); o[1] = f2bs(d[1]);
        o[2] = f2bs(d[2]); o[3] = f2bs(d[3]);
        short* Gd = tb ? Gw_w : &Gh_s[w][0][0];
        *(short4v*)(Gd + col * 68 + 16 * t + grp * 4) = o;
      }
    }
  }
  __asm__ volatile("s_waitcnt lgkmcnt(0)" ::: "memory");

  float gw[8];
#pragma unroll
  for (int t = 0; t < 2; ++t)
#pragma unroll
    for (int r = 0; r < 4; ++r)
      gw[t * 4 + r] =
          bs2f(Gw_w[col * 68 + t * 16 + grp * 4 + r - j0 - col + 31]);

  const short8 a_one = {0x3F80, 0x3F80, 0x3F80, 0x3F80,
                        0x3F80, 0x3F80, 0x3F80, 0x3F80};

  f32x4 acc0 = {0.f, 0.f, 0.f, 0.f};
  f32x4 acc1 = {0.f, 0.f, 0.f, 0.f};
  f32x4 accl = {0.f, 0.f, 0.f, 0.f};

  short8 cvA0p = {}, cvA1p = {}, cvB0p = {}, cvB1p = {};

  *(short8*)&kvb[0][w][lane * 8] = stgK;
  *(short8*)&kvb[0][4 + w][lane * 8] = stgV;
  __syncthreads();

#pragma unroll 2
  for (int it = 0; it < 16; ++it) {
    const int cur = it & 1;
    if (it < 15) {
      stgK = *(const short8*)(gK + (size_t)(it + 1) * 2048);
      stgV = *(const short8*)(gV + (size_t)(it + 1) * 2048);
    }
    short8 ck0  = *(const short8*)&kvb[cur][0][lane * 8];
    short8 ck1  = *(const short8*)&kvb[cur][1][lane * 8];
    short8 ck2  = *(const short8*)&kvb[cur][2][lane * 8];
    short8 ck3  = *(const short8*)&kvb[cur][3][lane * 8];
    short8 cva0 = *(const short8*)&kvb[cur][4][lane * 8];
    short8 cva1 = *(const short8*)&kvb[cur][5][lane * 8];
    short8 cvb0 = *(const short8*)&kvb[cur][6][lane * 8];
    short8 cvb1 = *(const short8*)&kvb[cur][7][lane * 8];

    f32x4 s0 = __builtin_amdgcn_mfma_f32_16x16x32_bf16(
        ck0, b_q, (f32x4){0.f, 0.f, 0.f, 0.f}, 0, 0, 0);
    f32x4 s1 = __builtin_amdgcn_mfma_f32_16x16x32_bf16(
        ck1, b_q, (f32x4){0.f, 0.f, 0.f, 0.f}, 0, 0, 0);
    f32x4 s2 = __builtin_amdgcn_mfma_f32_16x16x32_bf16(
        ck2, b_q, (f32x4){0.f, 0.f, 0.f, 0.f}, 0, 0, 0);
    f32x4 s3 = __builtin_amdgcn_mfma_f32_16x16x32_bf16(
        ck3, b_q, (f32x4){0.f, 0.f, 0.f, 0.f}, 0, 0, 0);

    if (it > 0) {
      short8 pA = *(const short8*)&Pt_s[w][0][col][g8];
      short8 pB = *(const short8*)&Pt_s[w][1][col][g8];
      acc0 = __builtin_amdgcn_mfma_f32_16x16x32_bf16(cvA0p, pA, acc0, 0, 0, 0);
      acc0 = __builtin_amdgcn_mfma_f32_16x16x32_bf16(cvB0p, pB, acc0, 0, 0, 0);
      acc1 = __builtin_amdgcn_mfma_f32_16x16x32_bf16(cvA1p, pA, acc1, 0, 0, 0);
      acc1 = __builtin_amdgcn_mfma_f32_16x16x32_bf16(cvB1p, pB, acc1, 0, 0, 0);
      accl = __builtin_amdgcn_mfma_f32_16x16x32_bf16(a_one, pA, accl, 0, 0, 0);
      accl = __builtin_amdgcn_mfma_f32_16x16x32_bf16(a_one, pB, accl, 0, 0, 0);
    }

    float ghA = bs2f(Gh_s[w][col][2 * it - i + 31]);
    float ghB = bs2f(Gh_s[w][col][2 * it + 1 - i + 31]);
    short4v p0, p1, p2, p3;
#pragma unroll
    for (int r = 0; r < 4; ++r) p0[r] = f2bs(fexp2(s0[r] + ghA + gw[r]));
#pragma unroll
    for (int r = 0; r < 4; ++r) p1[r] = f2bs(fexp2(s1[r] + ghA + gw[4 + r]));
#pragma unroll
    for (int r = 0; r < 4; ++r) p2[r] = f2bs(fexp2(s2[r] + ghB + gw[r]));
#pragma unroll
    for (int r = 0; r < 4; ++r) p3[r] = f2bs(fexp2(s3[r] + ghB + gw[4 + r]));
    *(short4v*)&Pt_s[w][0][col][grp * 4] = p0;
    *(short4v*)&Pt_s[w][0][col][16 + grp * 4] = p1;
    *(short4v*)&Pt_s[w][1][col][grp * 4] = p2;
    *(short4v*)&Pt_s[w][1][col][16 + grp * 4] = p3;

    if (it < 15) {
      *(short8*)&kvb[cur ^ 1][w][lane * 8] = stgK;
      *(short8*)&kvb[cur ^ 1][4 + w][lane * 8] = stgV;
    }
    cvA0p = cva0; cvA1p = cva1; cvB0p = cvb0; cvB1p = cvb1;
    __syncthreads();
  }

  {
    short8 pA = *(const short8*)&Pt_s[w][0][col][g8];
    short8 pB = *(const short8*)&Pt_s[w][1][col][g8];
    acc0 = __builtin_amdgcn_mfma_f32_16x16x32_bf16(cvA0p, pA, acc0, 0, 0, 0);
    acc0 = __builtin_amdgcn_mfma_f32_16x16x32_bf16(cvB0p, pB, acc0, 0, 0, 0);
    acc1 = __builtin_amdgcn_mfma_f32_16x16x32_bf16(cvA1p, pA, acc1, 0, 0, 0);
    acc1 = __builtin_amdgcn_mfma_f32_16x16x32_bf16(cvB1p, pB, acc1, 0, 0, 0);
    accl = __builtin_amdgcn_mfma_f32_16x16x32_bf16(a_one, pA, accl, 0, 0, 0);
    accl = __builtin_amdgcn_mfma_f32_16x16x32_bf16(a_one, pB, accl, 0, 0, 0);
  }

  float rn = 1.0f / accl[0];
  const int bq = bnh >> 3, nh = bnh & 7;
  short* amb = amt2 + (((size_t)bq * 64 + qt) * 8 + nh) * 512 +
               (grp >> 1) * 128 + col * 8 + (grp & 1) * 4;
  short4v o4a, o4b;
#pragma unroll
  for (int r = 0; r < 4; ++r) {
    o4a[r] = f2bs(acc0[r] * rn);
    o4b[r] = f2bs(acc1[r] * rn);
  }
  *(short4v*)&amb[0] = o4a;
  *(short4v*)&amb[256] = o4b;
}

// ---------------------------------------------------------------------------
// Kernel 3 (tail): conv (bid<256, ALL 256 out-ch per block, single-stage
// 53.9KB LDS) + proj (bid>=256).  grid 512, block 256.
// ---------------------------------------------------------------------------
__global__ __launch_bounds__(256) void tail(
    const short* __restrict__ xt, const short* __restrict__ Wb2,
    const float* __restrict__ b_out,
    const short* __restrict__ Wa2, const short* __restrict__ amt2,
    const float* __restrict__ b_attn, float* __restrict__ out) {
  __shared__ __align__(16) short xs[3 * 34 * 264];   // 53856B
  const int bid = blockIdx.x;
  const int tid = threadIdx.x;
  const int w = tid >> 6, lane = tid & 63;
  const int col = lane & 15, grp = lane >> 4, g8 = grp * 8;

  if (bid < 256) {
    // ---- conv: one block = one (r0, bb), all 256 out-ch ----
    const int r0 = bid & 31, bb = bid >> 5;
    {
      const short* src = xt + (((size_t)bb * 34 + r0) * 34) * 256;
      for (int g = tid; g < 3264; g += 256) {       // 3*34*32 8-short groups
        int row = g / 1088;                          // 34*32
        int rem = g - row * 1088;
        int cc = rem >> 5, chg = rem & 31;
        short8 v = *(const short8*)(src + (row * 34 + cc) * 256 + chg * 8);
        *(short8*)(xs + (row * 34 + cc) * 264 + chg * 8) = v;
      }
    }
    __syncthreads();

    const short* wbase = Wb2 + lane * 8;
    f32x4 acc[4][2] = {};   // [k: o16 = w+4k][p-tile]

#pragma unroll 1
    for (int tap = 0; tap < 9; ++tap) {
      const int u = (tap * 11) >> 5, v = tap - 3 * u;   // exact for tap<9
      const short* wt = wbase + (size_t)tap * 65536;
      const short* xb0 = xs + (u * 34 + col + v) * 264 + g8;
      const short* xb1 = xs + (u * 34 + col + 16 + v) * 264 + g8;
#pragma unroll
      for (int c8 = 0; c8 < 8; ++c8) {
        const int chb = c8 * 32;
        short8 b0 = *(const short8*)(xb0 + chb);
        short8 b1 = *(const short8*)(xb1 + chb);
#pragma unroll
        for (int k = 0; k < 4; ++k) {
          short8 ak = *(const short8*)(wt + (size_t)((w + 4 * k) * 8 + c8) * 512);
          acc[k][0] = __builtin_amdgcn_mfma_f32_16x16x32_bf16(ak, b0, acc[k][0], 0, 0, 0);
          acc[k][1] = __builtin_amdgcn_mfma_f32_16x16x32_bf16(ak, b1, acc[k][1], 0, 0, 0);
        }
      }
    }

    float* ob = out + (size_t)bb * 512 * 1024 + r0 * 32;
#pragma unroll
    for (int k = 0; k < 4; ++k) {
      const int obk = (w + 4 * k) * 16;
#pragma unroll
      for (int r = 0; r < 4; ++r) {
        int o = obk + grp * 4 + r;
        float bv = b_out[o];
        ob[(size_t)o * 1024 + col]      = acc[k][0][r] + bv;
        ob[(size_t)o * 1024 + 16 + col] = acc[k][1][r] + bv;
      }
    }
  } else {
    // ---- proj path ----
    const int t = bid - 256;
    const int bx = t & 15, by = (t >> 4) & 1, b = t >> 5;
    const int p0 = bx * 64;
    const int ob = by * 128 + w * 16;
    const int o16 = ob >> 4;

    const short* wbase = Wa2 + lane * 8;
    const short* xpb = amt2 + (((size_t)b * 64 + bx * 4) * 8) * 512 + lane * 8;

    f32x4 acc[2][4] = {};
#pragma unroll
    for (int c8 = 0; c8 < 8; ++c8) {
      short8 a0 = *(const short8*)(wbase + (size_t)(o16 * 8 + c8) * 512);
      short8 a1 = *(const short8*)(wbase + (size_t)((o16 + 4) * 8 + c8) * 512);
      short8 b0 = *(const short8*)(xpb + c8 * 512);
      short8 b1 = *(const short8*)(xpb + 4096 + c8 * 512);
      short8 b2 = *(const short8*)(xpb + 8192 + c8 * 512);
      short8 b3 = *(const short8*)(xpb + 12288 + c8 * 512);
      acc[0][0] = __builtin_amdgcn_mfma_f32_16x16x32_bf16(a0, b0, acc[0][0], 0, 0, 0);
      acc[0][1] = __builtin_amdgcn_mfma_f32_16x16x32_bf16(a0, b1, acc[0][1], 0, 0, 0);
      acc[0][2] = __builtin_amdgcn_mfma_f32_16x16x32_bf16(a0, b2, acc[0][2], 0, 0, 0);
      acc[0][3] = __builtin_amdgcn_mfma_f32_16x16x32_bf16(a0, b3, acc[0][3], 0, 0, 0);
      acc[1][0] = __builtin_amdgcn_mfma_f32_16x16x32_bf16(a1, b0, acc[1][0], 0, 0, 0);
      acc[1][1] = __builtin_amdgcn_mfma_f32_16x16x32_bf16(a1, b1, acc[1][1], 0, 0, 0);
      acc[1][2] = __builtin_amdgcn_mfma_f32_16x16x32_bf16(a1, b2, acc[1][2], 0, 0, 0);
      acc[1][3] = __builtin_amdgcn_mfma_f32_16x16x32_bf16(a1, b3, acc[1][3], 0, 0, 0);
    }

#pragma unroll
    for (int j = 0; j < 2; ++j) {
      const int obase = ob + j * 64 + grp * 4;
      float bv[4];
#pragma unroll
      for (int r = 0; r < 4; ++r) bv[r] = b_attn[obase + r];
#pragma unroll
      for (int pp = 0; pp < 4; ++pp) {
        const int p = p0 + pp * 16 + col;
#pragma unroll
        for (int r = 0; r < 4; ++r)
          out[((size_t)b * 512 + 256 + obase + r) * 1024 + p] =
              acc[j][pp][r] + bv[r];
      }
    }
  }
}

// ---------------------------------------------------------------------------
extern "C" void kernel_launch(void* const* d_in, const int* in_sizes, int n_in,
                              void* d_out, int out_size, void* d_ws, size_t ws_size,
                              hipStream_t stream) {
  const float* x      = (const float*)d_in[0];
  const float* w_qkv  = (const float*)d_in[1];
  const float* b_qkv  = (const float*)d_in[2];
  const float* w_attn = (const float*)d_in[3];
  const float* b_attn = (const float*)d_in[4];
  const float* w_out  = (const float*)d_in[5];
  const float* b_out  = (const float*)d_in[6];
  const float* relw   = (const float*)d_in[7];
  const float* relh   = (const float*)d_in[8];
  float* out = (float*)d_out;

  short* qsb  = (short*)d_ws;
  short* ksb2 = qsb + (size_t)2 * 1024 * 1024;
  short* vtb2 = ksb2 + (size_t)2 * 1024 * 1024;
  short* amt2 = (short*)((char*)d_ws + (size_t)12 * 1024 * 1024);
  short* xt   = (short*)((char*)d_ws + (size_t)16 * 1024 * 1024);
  short* xb2  = (short*)((char*)d_ws + (size_t)21 * 1024 * 1024);
  short* Wq2  = (short*)((char*)d_ws + (size_t)25 * 1024 * 1024);
  short* Wa2  = (short*)((char*)d_ws + (size_t)25 * 1024 * 1024 + 512 * 1024);
  short* Wb2  = (short*)((char*)d_ws + (size_t)26 * 1024 * 1024);

  prep<<<1552, 256, 0, stream>>>(x, xt, xb2, w_out, Wb2, w_qkv, Wq2,
                                 w_attn, Wa2);
  qkv_mfma<<<dim3(16, 6, 8), 256, 0, stream>>>(Wq2, xb2, b_qkv, qsb, ksb2, vtb2);
  attn_mfma<<<dim3(16, 64), 256, 0, stream>>>(qsb, ksb2, vtb2, relw, relh, amt2);
  tail<<<512, 256, 0, stream>>>(xt, Wb2, b_out, Wa2, amt2, b_attn, out);
}

// Round 12
// 141.847 us; speedup vs baseline: 1.1750x; 1.1750x over previous
//
#include <hip/hip_runtime.h>
#include <hip/hip_bf16.h>

// Round-14: qkv/proj -> bf16 MFMA GEMMs (-33us).
// Round-15/16: coalesced prepass, fragment-tiled xb2 (-17us).
// Round-19: fragment-tiled ALL MFMA operands (-18us).
// Round-20: merged 6->4 launches + exp2 softmax (145.2us VERIFIED).
// Round-21/22: grid-sync fusion -> harness deaths.  OFF THE TABLE.
// Round-23/24: conv restage experiments BOTH regressed (155, 166.7).
//   Counters falsified the traffic theory: FETCH unchanged (L2 absorbed
//   oh-duplicate staging); r24 dropped occupancy 19->11% and tripled bank
//   conflicts.  Ranking: r7 full-stage oh-split > 2-half > merged.
// Round-25 (this): revert tail to the r7 conv (full 53.9KB stage, oh-split,
//   512 conv blocks) with two deltas: (1) proj blocks FIRST so their ~5us
//   overlaps conv instead of serializing after it (512 co-resident slots);
//   (2) tap loop unroll 1->2 so next-tap weight loads hoist over current
//   MFMAs (tail was 7-9% MfmaUtil, everything idle = load-latency-bound).

typedef __hip_bfloat16 bf16;
using short8 = __attribute__((ext_vector_type(8))) short;
using short4v = __attribute__((ext_vector_type(4))) short;
using f32x4 = __attribute__((ext_vector_type(4))) float;

__device__ __forceinline__ short f2bs(float f) {
  union { bf16 b; short s; } u; u.b = __float2bfloat16(f); return u.s;
}
__device__ __forceinline__ float bs2f(short s) {
  union { unsigned u; float f; } x; x.u = ((unsigned)(unsigned short)s) << 16;
  return x.f;
}
__device__ __forceinline__ float fexp2(float x) {
  float r; asm("v_exp_f32 %0, %1" : "=v"(r) : "v"(x)); return r;
}

// Fragment-tile address for a [O][256] bf16 weight matrix.
__device__ __forceinline__ size_t wtile(int o, int c) {
  return ((size_t)((o >> 4) * 8 + (c >> 5)) * 512) +
         (((c >> 3) & 3) * 16 + (o & 15)) * 8 + (c & 7);
}

// ---------------------------------------------------------------------------
// Kernel 0 (prep): xpose + all weight packs, blockIdx-partitioned.
// grid 1552, block 256.  LDS: union of xls (16896B) / ws (9216B).
// ---------------------------------------------------------------------------
__global__ __launch_bounds__(256) void prep(
    const float* __restrict__ X, short* __restrict__ xt,
    short* __restrict__ xb2,
    const float* __restrict__ Wc, short* __restrict__ Wb2,
    const float* __restrict__ wq, short* __restrict__ Wq2,
    const float* __restrict__ wa, short* __restrict__ Wa2) {
  __shared__ __align__(16) char smem[16896];
  const int bid = blockIdx.x;
  const int tid = threadIdx.x;
  if (bid < 272) {
    const int b = bid / 34, r = bid - (bid / 34) * 34;   // r in 0..33
    if (r == 0 || r == 33) {                  // full zero halo row
      short8 z = {};
      short* dst = xt + (((size_t)b * 34 + r) * 34) * 256;
      for (int g = tid; g < 1088; g += 256) *(short8*)(dst + g * 8) = z;
      return;
    }
    short (*xls)[264] = (short(*)[264])smem;  // [p][c], pitch 264
    {
      const float* src = X + (size_t)b * 256 * 1024 + (r - 1) * 32;
      for (int it = 0; it < 8; ++it) {
        int idx = it * 256 + tid;
        int c = idx >> 3, pq = idx & 7;
        float4 f4 = *(const float4*)(src + (size_t)c * 1024 + pq * 4);
        xls[pq * 4 + 0][c] = f2bs(f4.x);
        xls[pq * 4 + 1][c] = f2bs(f4.y);
        xls[pq * 4 + 2][c] = f2bs(f4.z);
        xls[pq * 4 + 3][c] = f2bs(f4.w);
      }
    }
    __syncthreads();
    {
      short* dst = xt + (((size_t)b * 34 + r) * 34) * 256;
      for (int it = 0; it < 4; ++it) {
        int idx = it * 256 + tid;
        int cc = idx >> 5, co = idx & 31;
        short8 v = *(const short8*)&xls[cc][co * 8];
        *(short8*)(dst + (cc + 1) * 256 + co * 8) = v;
      }
      if (tid < 64) {
        short8 z = {};
        int cce = (tid >> 5) * 33, co = tid & 31;
        *(short8*)(dst + cce * 256 + co * 8) = z;
      }
    }
    {
      short* dst = xb2 + (((size_t)b * 64 + (r - 1) * 2) * 8) * 512;
      for (int it = 0; it < 4; ++it) {
        int g = it * 256 + tid;
        int half = g >> 9, c8 = (g >> 6) & 7, grp = (g >> 4) & 3, pcol = g & 15;
        short8 v = *(const short8*)&xls[half * 16 + pcol][c8 * 32 + grp * 8];
        *(short8*)(dst + ((half * 8 + c8) * 64 + grp * 16 + pcol) * 8) = v;
      }
    }
  } else if (bid < 528) {
    float* ws = (float*)smem;                  // one o's [c][tap] block
    const int o = bid - 272;
    const float* src = Wc + (size_t)o * 2304;
    for (int it = 0; it < 9; ++it) ws[it * 256 + tid] = src[it * 256 + tid];
    __syncthreads();
#pragma unroll
    for (int tap = 0; tap < 9; ++tap)
      Wb2[(size_t)tap * 65536 + wtile(o, tid)] = f2bs(ws[tid * 9 + tap]);
  } else if (bid < 1296) {
    const int o = bid - 528;
    Wq2[wtile(o, tid)] = f2bs(wq[o * 256 + tid]);
  } else {
    const int o = bid - 1296;
    Wa2[wtile(o, tid)] = f2bs(wa[o * 256 + tid]);
  }
}

// ---------------------------------------------------------------------------
// Kernel 1: QKV 1x1 conv as bf16 MFMA GEMM, all operands lane-linear.
// grid (16, 6, 8), block 256.
// ---------------------------------------------------------------------------
__global__ __launch_bounds__(256) void qkv_mfma(
    const short* __restrict__ Wq2, const short* __restrict__ xb2,
    const float* __restrict__ bias,
    short* __restrict__ qsb, short* __restrict__ ksb2, short* __restrict__ vtb2) {
  const int tid = threadIdx.x;
  const int w = tid >> 6, lane = tid & 63;
  const int col = lane & 15, grp = lane >> 4;
  const int b = blockIdx.z;
  const int bx = blockIdx.x;
  const int p0 = bx * 64;
  const int ob = blockIdx.y * 128 + w * 16;
  const int o16 = ob >> 4;

  const short* wbase = Wq2 + lane * 8;
  const short* xpb = xb2 + (((size_t)b * 64 + bx * 4) * 8) * 512 + lane * 8;

  f32x4 acc[2][4] = {};
#pragma unroll
  for (int c8 = 0; c8 < 8; ++c8) {
    short8 a0 = *(const short8*)(wbase + (size_t)(o16 * 8 + c8) * 512);
    short8 a1 = *(const short8*)(wbase + (size_t)((o16 + 4) * 8 + c8) * 512);
    short8 b0 = *(const short8*)(xpb + c8 * 512);
    short8 b1 = *(const short8*)(xpb + 4096 + c8 * 512);
    short8 b2 = *(const short8*)(xpb + 8192 + c8 * 512);
    short8 b3 = *(const short8*)(xpb + 12288 + c8 * 512);
    acc[0][0] = __builtin_amdgcn_mfma_f32_16x16x32_bf16(a0, b0, acc[0][0], 0, 0, 0);
    acc[0][1] = __builtin_amdgcn_mfma_f32_16x16x32_bf16(a0, b1, acc[0][1], 0, 0, 0);
    acc[0][2] = __builtin_amdgcn_mfma_f32_16x16x32_bf16(a0, b2, acc[0][2], 0, 0, 0);
    acc[0][3] = __builtin_amdgcn_mfma_f32_16x16x32_bf16(a0, b3, acc[0][3], 0, 0, 0);
    acc[1][0] = __builtin_amdgcn_mfma_f32_16x16x32_bf16(a1, b0, acc[1][0], 0, 0, 0);
    acc[1][1] = __builtin_amdgcn_mfma_f32_16x16x32_bf16(a1, b1, acc[1][1], 0, 0, 0);
    acc[1][2] = __builtin_amdgcn_mfma_f32_16x16x32_bf16(a1, b2, acc[1][2], 0, 0, 0);
    acc[1][3] = __builtin_amdgcn_mfma_f32_16x16x32_bf16(a1, b3, acc[1][3], 0, 0, 0);
  }

  const float qscale = 0.25503486f;  // 32^-0.5 * log2(e)
#pragma unroll
  for (int j = 0; j < 2; ++j) {
    const int obase = ob + j * 64 + grp * 4;
    const int sect = obase >> 8;
    const int nh = (obase >> 5) & 7;
    const int d0 = obase & 31;
    const size_t hb = ((size_t)(b * 8 + nh)) * 1024;
    const size_t hb2 = ((size_t)(b * 8 + nh)) * 32768;
    float bv[4];
#pragma unroll
    for (int r = 0; r < 4; ++r) bv[r] = bias[obase + r];
    if (sect == 0) {
#pragma unroll
      for (int pp = 0; pp < 4; ++pp) {
        const int p = p0 + pp * 16 + col;
        short4v o4;
#pragma unroll
        for (int r = 0; r < 4; ++r)
          o4[r] = f2bs((acc[j][pp][r] + bv[r]) * qscale);
        *(short4v*)&qsb[(hb + p) * 32 + d0] = o4;
      }
    } else if (sect == 1) {
      const size_t kb = hb2 + (size_t)bx * 2048 + (w & 1) * 256 +
                        (grp >> 1) * 128 + col * 8 + (grp & 1) * 4;
#pragma unroll
      for (int pp = 0; pp < 4; ++pp) {
        short4v o4;
#pragma unroll
        for (int r = 0; r < 4; ++r)
          o4[r] = f2bs(acc[j][pp][r] + bv[r]);
        *(short4v*)&ksb2[kb + pp * 512] = o4;
      }
    } else {
      const size_t vb0 = hb2 + (size_t)bx * 2048 + (size_t)(w & 1) * 512 +
                         (col >> 3) * 128 + (grp * 4) * 8 + (col & 7);
#pragma unroll
      for (int pp = 0; pp < 4; ++pp) {
        const size_t vb = vb0 + (pp >> 1) * 1024 + (pp & 1) * 256;
#pragma unroll
        for (int r = 0; r < 4; ++r)
          vtb2[vb + r * 8] = f2bs(acc[j][pp][r] + bv[r]);
      }
    }
  }
}

// ---------------------------------------------------------------------------
// Kernel 2: pipelined transposed MFMA flash attention; lane-linear K/V
// staging; exp2 softmax.  grid (16, 64), block 256.  LDS 35.3KB, 4 blk/CU.
// ---------------------------------------------------------------------------
__global__ __launch_bounds__(256, 4) void attn_mfma(
    const short* __restrict__ qsb, const short* __restrict__ ksb2,
    const short* __restrict__ vtb2,
    const float* __restrict__ relw_g, const float* __restrict__ relh_g,
    short* __restrict__ amt2) {
  const int tid = threadIdx.x;
  const int w = tid >> 6, lane = tid & 63;
  const int col = lane & 15, grp = lane >> 4, g8 = grp * 8;
  const int qt = blockIdx.x * 4 + w;       // q-tile 0..63
  const int bnh = blockIdx.y;
  const int q0 = qt * 16;
  const int i = qt >> 1;
  const int j0 = (qt & 1) * 16;

  const short* Qb = qsb + (size_t)bnh * 32768;

  __shared__ short Gh_s[4][16][68];     // [wave][q][m]        8704B
  __shared__ short kvb[2][8][512];      // [slot][frag][...]  16384B
  __shared__ short Pt_s[4][2][16][40];  // [wave][half][q][key] 10240B
  short* Gw_w = &Pt_s[w][0][0][0];      // scratch alias (wave-private)

  const short* gK = ksb2 + (size_t)bnh * 32768 + w * 512 + lane * 8;
  const short* gV = vtb2 + (size_t)bnh * 32768 + w * 512 + lane * 8;

  short8 stgK = *(const short8*)gK;
  short8 stgV = *(const short8*)gV;

  short8 b_q = *(const short8*)(Qb + (q0 + col) * 32 + g8);

  {
    const float* rels[2] = {relh_g, relw_g};
#pragma unroll
    for (int tb = 0; tb < 2; ++tb) {
      const float* relg = rels[tb];
#pragma unroll
      for (int t = 0; t < 4; ++t) {
        int m = 16 * t + col;
        int mc = m > 62 ? 62 : m;
        const float* rp = relg + mc * 32 + g8;
        float4 f0 = *(const float4*)rp;
        float4 f1 = *(const float4*)(rp + 4);
        short8 ar;
        ar[0] = f2bs(f0.x); ar[1] = f2bs(f0.y);
        ar[2] = f2bs(f0.z); ar[3] = f2bs(f0.w);
        ar[4] = f2bs(f1.x); ar[5] = f2bs(f1.y);
        ar[6] = f2bs(f1.z); ar[7] = f2bs(f1.w);
        f32x4 d = __builtin_amdgcn_mfma_f32_16x16x32_bf16(
            ar, b_q, (f32x4){0.f, 0.f, 0.f, 0.f}, 0, 0, 0);
        short4v o;
        o[0] = f2bs(d[0]); o[1] = f2bs(d[1]);
        o[2] = f2bs(d[2]); o[3] = f2bs(d[3]);
        short* Gd = tb ? Gw_w : &Gh_s[w][0][0];
        *(short4v*)(Gd + col * 68 + 16 * t + grp * 4) = o;
      }
    }
  }
  __asm__ volatile("s_waitcnt lgkmcnt(0)" ::: "memory");

  float gw[8];
#pragma unroll
  for (int t = 0; t < 2; ++t)
#pragma unroll
    for (int r = 0; r < 4; ++r)
      gw[t * 4 + r] =
          bs2f(Gw_w[col * 68 + t * 16 + grp * 4 + r - j0 - col + 31]);

  const short8 a_one = {0x3F80, 0x3F80, 0x3F80, 0x3F80,
                        0x3F80, 0x3F80, 0x3F80, 0x3F80};

  f32x4 acc0 = {0.f, 0.f, 0.f, 0.f};
  f32x4 acc1 = {0.f, 0.f, 0.f, 0.f};
  f32x4 accl = {0.f, 0.f, 0.f, 0.f};

  short8 cvA0p = {}, cvA1p = {}, cvB0p = {}, cvB1p = {};

  *(short8*)&kvb[0][w][lane * 8] = stgK;
  *(short8*)&kvb[0][4 + w][lane * 8] = stgV;
  __syncthreads();

#pragma unroll 2
  for (int it = 0; it < 16; ++it) {
    const int cur = it & 1;
    if (it < 15) {
      stgK = *(const short8*)(gK + (size_t)(it + 1) * 2048);
      stgV = *(const short8*)(gV + (size_t)(it + 1) * 2048);
    }
    short8 ck0  = *(const short8*)&kvb[cur][0][lane * 8];
    short8 ck1  = *(const short8*)&kvb[cur][1][lane * 8];
    short8 ck2  = *(const short8*)&kvb[cur][2][lane * 8];
    short8 ck3  = *(const short8*)&kvb[cur][3][lane * 8];
    short8 cva0 = *(const short8*)&kvb[cur][4][lane * 8];
    short8 cva1 = *(const short8*)&kvb[cur][5][lane * 8];
    short8 cvb0 = *(const short8*)&kvb[cur][6][lane * 8];
    short8 cvb1 = *(const short8*)&kvb[cur][7][lane * 8];

    f32x4 s0 = __builtin_amdgcn_mfma_f32_16x16x32_bf16(
        ck0, b_q, (f32x4){0.f, 0.f, 0.f, 0.f}, 0, 0, 0);
    f32x4 s1 = __builtin_amdgcn_mfma_f32_16x16x32_bf16(
        ck1, b_q, (f32x4){0.f, 0.f, 0.f, 0.f}, 0, 0, 0);
    f32x4 s2 = __builtin_amdgcn_mfma_f32_16x16x32_bf16(
        ck2, b_q, (f32x4){0.f, 0.f, 0.f, 0.f}, 0, 0, 0);
    f32x4 s3 = __builtin_amdgcn_mfma_f32_16x16x32_bf16(
        ck3, b_q, (f32x4){0.f, 0.f, 0.f, 0.f}, 0, 0, 0);

    if (it > 0) {
      short8 pA = *(const short8*)&Pt_s[w][0][col][g8];
      short8 pB = *(const short8*)&Pt_s[w][1][col][g8];
      acc0 = __builtin_amdgcn_mfma_f32_16x16x32_bf16(cvA0p, pA, acc0, 0, 0, 0);
      acc0 = __builtin_amdgcn_mfma_f32_16x16x32_bf16(cvB0p, pB, acc0, 0, 0, 0);
      acc1 = __builtin_amdgcn_mfma_f32_16x16x32_bf16(cvA1p, pA, acc1, 0, 0, 0);
      acc1 = __builtin_amdgcn_mfma_f32_16x16x32_bf16(cvB1p, pB, acc1, 0, 0, 0);
      accl = __builtin_amdgcn_mfma_f32_16x16x32_bf16(a_one, pA, accl, 0, 0, 0);
      accl = __builtin_amdgcn_mfma_f32_16x16x32_bf16(a_one, pB, accl, 0, 0, 0);
    }

    float ghA = bs2f(Gh_s[w][col][2 * it - i + 31]);
    float ghB = bs2f(Gh_s[w][col][2 * it + 1 - i + 31]);
    short4v p0, p1, p2, p3;
#pragma unroll
    for (int r = 0; r < 4; ++r) p0[r] = f2bs(fexp2(s0[r] + ghA + gw[r]));
#pragma unroll
    for (int r = 0; r < 4; ++r) p1[r] = f2bs(fexp2(s1[r] + ghA + gw[4 + r]));
#pragma unroll
    for (int r = 0; r < 4; ++r) p2[r] = f2bs(fexp2(s2[r] + ghB + gw[r]));
#pragma unroll
    for (int r = 0; r < 4; ++r) p3[r] = f2bs(fexp2(s3[r] + ghB + gw[4 + r]));
    *(short4v*)&Pt_s[w][0][col][grp * 4] = p0;
    *(short4v*)&Pt_s[w][0][col][16 + grp * 4] = p1;
    *(short4v*)&Pt_s[w][1][col][grp * 4] = p2;
    *(short4v*)&Pt_s[w][1][col][16 + grp * 4] = p3;

    if (it < 15) {
      *(short8*)&kvb[cur ^ 1][w][lane * 8] = stgK;
      *(short8*)&kvb[cur ^ 1][4 + w][lane * 8] = stgV;
    }
    cvA0p = cva0; cvA1p = cva1; cvB0p = cvb0; cvB1p = cvb1;
    __syncthreads();
  }

  {
    short8 pA = *(const short8*)&Pt_s[w][0][col][g8];
    short8 pB = *(const short8*)&Pt_s[w][1][col][g8];
    acc0 = __builtin_amdgcn_mfma_f32_16x16x32_bf16(cvA0p, pA, acc0, 0, 0, 0);
    acc0 = __builtin_amdgcn_mfma_f32_16x16x32_bf16(cvB0p, pB, acc0, 0, 0, 0);
    acc1 = __builtin_amdgcn_mfma_f32_16x16x32_bf16(cvA1p, pA, acc1, 0, 0, 0);
    acc1 = __builtin_amdgcn_mfma_f32_16x16x32_bf16(cvB1p, pB, acc1, 0, 0, 0);
    accl = __builtin_amdgcn_mfma_f32_16x16x32_bf16(a_one, pA, accl, 0, 0, 0);
    accl = __builtin_amdgcn_mfma_f32_16x16x32_bf16(a_one, pB, accl, 0, 0, 0);
  }

  float rn = 1.0f / accl[0];
  const int bq = bnh >> 3, nh = bnh & 7;
  short* amb = amt2 + (((size_t)bq * 64 + qt) * 8 + nh) * 512 +
               (grp >> 1) * 128 + col * 8 + (grp & 1) * 4;
  short4v o4a, o4b;
#pragma unroll
  for (int r = 0; r < 4; ++r) {
    o4a[r] = f2bs(acc0[r] * rn);
    o4b[r] = f2bs(acc1[r] * rn);
  }
  *(short4v*)&amb[0] = o4a;
  *(short4v*)&amb[256] = o4b;
}

// ---------------------------------------------------------------------------
// Kernel 3 (tail): proj FIRST (bid<256, overlaps conv), then conv
// (bid 256..767, r7 structure: full 53.9KB stage, oh-split, tap unroll 2).
// grid 768, block 256.
// ---------------------------------------------------------------------------
__global__ __launch_bounds__(256) void tail(
    const short* __restrict__ xt, const short* __restrict__ Wb2,
    const float* __restrict__ b_out,
    const short* __restrict__ Wa2, const short* __restrict__ amt2,
    const float* __restrict__ b_attn, float* __restrict__ out) {
  __shared__ __align__(16) short xs[3 * 34 * 264];   // 53856B
  const int bid = blockIdx.x;
  const int tid = threadIdx.x;
  const int w = tid >> 6, lane = tid & 63;
  const int col = lane & 15, grp = lane >> 4, g8 = grp * 8;

  if (bid >= 256) {
    // ---- conv path (r7 structure) ----
    const int t = bid - 256;
    const int r0 = t & 31, oh = (t >> 5) & 1, bb = t >> 6;
    {
      const short* src = xt + (((size_t)bb * 34 + r0) * 34) * 256;
      for (int g = tid; g < 3264; g += 256) {       // 3*34*32 8-short groups
        int row = g / 1088;                          // 34*32
        int rem = g - row * 1088;
        int cc = rem >> 5, chg = rem & 31;
        short8 v = *(const short8*)(src + (row * 34 + cc) * 256 + chg * 8);
        *(short8*)(xs + (row * 34 + cc) * 264 + chg * 8) = v;
      }
    }
    __syncthreads();

    const int ob0 = oh * 128 + w * 16;    // first o-tile
    const int o16_0 = oh * 8 + w;         // ob0>>4
    const short* wbase = Wb2 + lane * 8;

    f32x4 acc00 = {0.f, 0.f, 0.f, 0.f};
    f32x4 acc01 = {0.f, 0.f, 0.f, 0.f};
    f32x4 acc10 = {0.f, 0.f, 0.f, 0.f};
    f32x4 acc11 = {0.f, 0.f, 0.f, 0.f};

#pragma unroll 2
    for (int tap = 0; tap < 9; ++tap) {
      const int u = (tap * 11) >> 5, v = tap - 3 * u;   // exact for tap<9
      const short* wt = wbase + (size_t)tap * 65536;
      const short* xb0 = xs + (u * 34 + col + v) * 264 + g8;
      const short* xb1 = xs + (u * 34 + col + 16 + v) * 264 + g8;
#pragma unroll
      for (int c8 = 0; c8 < 8; ++c8) {
        const int chb = c8 * 32;
        short8 a0 = *(const short8*)(wt + (size_t)(o16_0 * 8 + c8) * 512);
        short8 a1 = *(const short8*)(wt + (size_t)((o16_0 + 4) * 8 + c8) * 512);
        short8 b0 = *(const short8*)(xb0 + chb);
        short8 b1 = *(const short8*)(xb1 + chb);
        acc00 = __builtin_amdgcn_mfma_f32_16x16x32_bf16(a0, b0, acc00, 0, 0, 0);
        acc01 = __builtin_amdgcn_mfma_f32_16x16x32_bf16(a0, b1, acc01, 0, 0, 0);
        acc10 = __builtin_amdgcn_mfma_f32_16x16x32_bf16(a1, b0, acc10, 0, 0, 0);
        acc11 = __builtin_amdgcn_mfma_f32_16x16x32_bf16(a1, b1, acc11, 0, 0, 0);
      }
    }

    const int ob1 = ob0 + 64;
    float* ob = out + (size_t)bb * 512 * 1024 + r0 * 32;
#pragma unroll
    for (int r = 0; r < 4; ++r) {
      int o0 = ob0 + grp * 4 + r;
      int o1 = ob1 + grp * 4 + r;
      float bv0 = b_out[o0], bv1 = b_out[o1];
      ob[(size_t)o0 * 1024 + col]      = acc00[r] + bv0;
      ob[(size_t)o0 * 1024 + 16 + col] = acc01[r] + bv0;
      ob[(size_t)o1 * 1024 + col]      = acc10[r] + bv1;
      ob[(size_t)o1 * 1024 + 16 + col] = acc11[r] + bv1;
    }
  } else {
    // ---- proj path (runs first, overlaps conv) ----
    const int t = bid;
    const int bx = t & 15, by = (t >> 4) & 1, b = t >> 5;
    const int p0 = bx * 64;
    const int ob = by * 128 + w * 16;
    const int o16 = ob >> 4;

    const short* wbase = Wa2 + lane * 8;
    const short* xpb = amt2 + (((size_t)b * 64 + bx * 4) * 8) * 512 + lane * 8;

    f32x4 acc[2][4] = {};
#pragma unroll
    for (int c8 = 0; c8 < 8; ++c8) {
      short8 a0 = *(const short8*)(wbase + (size_t)(o16 * 8 + c8) * 512);
      short8 a1 = *(const short8*)(wbase + (size_t)((o16 + 4) * 8 + c8) * 512);
      short8 b0 = *(const short8*)(xpb + c8 * 512);
      short8 b1 = *(const short8*)(xpb + 4096 + c8 * 512);
      short8 b2 = *(const short8*)(xpb + 8192 + c8 * 512);
      short8 b3 = *(const short8*)(xpb + 12288 + c8 * 512);
      acc[0][0] = __builtin_amdgcn_mfma_f32_16x16x32_bf16(a0, b0, acc[0][0], 0, 0, 0);
      acc[0][1] = __builtin_amdgcn_mfma_f32_16x16x32_bf16(a0, b1, acc[0][1], 0, 0, 0);
      acc[0][2] = __builtin_amdgcn_mfma_f32_16x16x32_bf16(a0, b2, acc[0][2], 0, 0, 0);
      acc[0][3] = __builtin_amdgcn_mfma_f32_16x16x32_bf16(a0, b3, acc[0][3], 0, 0, 0);
      acc[1][0] = __builtin_amdgcn_mfma_f32_16x16x32_bf16(a1, b0, acc[1][0], 0, 0, 0);
      acc[1][1] = __builtin_amdgcn_mfma_f32_16x16x32_bf16(a1, b1, acc[1][1], 0, 0, 0);
      acc[1][2] = __builtin_amdgcn_mfma_f32_16x16x32_bf16(a1, b2, acc[1][2], 0, 0, 0);
      acc[1][3] = __builtin_amdgcn_mfma_f32_16x16x32_bf16(a1, b3, acc[1][3], 0, 0, 0);
    }

#pragma unroll
    for (int j = 0; j < 2; ++j) {
      const int obase = ob + j * 64 + grp * 4;
      float bv[4];
#pragma unroll
      for (int r = 0; r < 4; ++r) bv[r] = b_attn[obase + r];
#pragma unroll
      for (int pp = 0; pp < 4; ++pp) {
        const int p = p0 + pp * 16 + col;
#pragma unroll
        for (int r = 0; r < 4; ++r)
          out[((size_t)b * 512 + 256 + obase + r) * 1024 + p] =
              acc[j][pp][r] + bv[r];
      }
    }
  }
}

// ---------------------------------------------------------------------------
extern "C" void kernel_launch(void* const* d_in, const int* in_sizes, int n_in,
                              void* d_out, int out_size, void* d_ws, size_t ws_size,
                              hipStream_t stream) {
  const float* x      = (const float*)d_in[0];
  const float* w_qkv  = (const float*)d_in[1];
  const float* b_qkv  = (const float*)d_in[2];
  const float* w_attn = (const float*)d_in[3];
  const float* b_attn = (const float*)d_in[4];
  const float* w_out  = (const float*)d_in[5];
  const float* b_out  = (const float*)d_in[6];
  const float* relw   = (const float*)d_in[7];
  const float* relh   = (const float*)d_in[8];
  float* out = (float*)d_out;

  short* qsb  = (short*)d_ws;
  short* ksb2 = qsb + (size_t)2 * 1024 * 1024;
  short* vtb2 = ksb2 + (size_t)2 * 1024 * 1024;
  short* amt2 = (short*)((char*)d_ws + (size_t)12 * 1024 * 1024);
  short* xt   = (short*)((char*)d_ws + (size_t)16 * 1024 * 1024);
  short* xb2  = (short*)((char*)d_ws + (size_t)21 * 1024 * 1024);
  short* Wq2  = (short*)((char*)d_ws + (size_t)25 * 1024 * 1024);
  short* Wa2  = (short*)((char*)d_ws + (size_t)25 * 1024 * 1024 + 512 * 1024);
  short* Wb2  = (short*)((char*)d_ws + (size_t)26 * 1024 * 1024);

  prep<<<1552, 256, 0, stream>>>(x, xt, xb2, w_out, Wb2, w_qkv, Wq2,
                                 w_attn, Wa2);
  qkv_mfma<<<dim3(16, 6, 8), 256, 0, stream>>>(Wq2, xb2, b_qkv, qsb, ksb2, vtb2);
  attn_mfma<<<dim3(16, 64), 256, 0, stream>>>(qsb, ksb2, vtb2, relw, relh, amt2);
  tail<<<768, 256, 0, stream>>>(xt, Wb2, b_out, Wa2, amt2, b_attn, out);
}